// Round 11
// baseline (98.301 us; speedup 1.0000x reference)
//
#include <hip/hip_runtime.h>

// Problem constants (from reference setup_inputs):
//   pred_emb:   (N=2, C=80, H=512, W=512) float32
//   gt_objmask: (N=2, K=32, H=512, W=512) bool (1 byte/elem)
//   gt_classes: (N=2, K=32) int32
#define N_IMG 2
#define K_OBJ 32
#define C_CH  80
#define HW    (512 * 512)
#define NK    (N_IMG * K_OBJ)

#define BPN 32                    // blocks per (n,k)
#define BT  256                   // threads per block
#define SPAN (BPN * BT)           // 8192 thread-slots per (n,k)
#define NV16 (HW / 16)            // 16384 16-elem groups per (n,k)
#define ITERS (NV16 / SPAN)       // = 2, compile-time

// ws layout (dwords from ws base):
//   [0, 6144)        partials: [blk][comp][nk], comp in {cnt,s,s2}
//   [6144, 6208)     mean[nk]
//   [6208, 6272)     var[nk]
//   [6272, 6274)     per-image part
//   [8192, 8192+2144) arrival counters (uint), stride 32 dwords = 128 B/line:
//                     nk counters [0..63], image counters [64..65], global [66]
#define P_STRIDE (3 * NK)
#define WS_MEAN  (BPN * P_STRIDE)        // 6144
#define WS_VAR   (WS_MEAN + NK)          // 6208
#define WS_PIMG  (WS_VAR + NK)           // 6272
#define CNT_BASE 8192
#define CNT_STRIDE 32
#define N_CNT (NK + N_IMG + 1)           // 67
#define CNT_WORDS (CNT_STRIDE * N_CNT)   // 2144

__global__ void zero_cnt(unsigned int* __restrict__ cntp) {
    const int i = threadIdx.x;
    #pragma unroll
    for (int r = 0; r < (CNT_WORDS + 255) / 256; ++r) {
        const int idx = i + r * 256;
        if (idx < CNT_WORDS) cntp[idx] = 0u;
    }
}

__global__ __launch_bounds__(BT) void fused_kernel(
    const float* __restrict__ pred,
    const unsigned char* __restrict__ mask,
    const int* __restrict__ classes,
    float* __restrict__ ws,
    float* __restrict__ out)
{
    const int nk  = blockIdx.x / BPN;
    const int blk = blockIdx.x % BPN;
    const int n   = nk / K_OBJ;
    const int c   = classes[nk];

    const float4* __restrict__ embv =
        (const float4*)(pred + (size_t)(n * C_CH + c) * HW);
    const uint4* __restrict__ mv =
        (const uint4*)(mask + (size_t)nk * HW);

    unsigned int cnt_i = 0;
    float s = 0.0f, s2 = 0.0f;
    const int base = blk * BT + threadIdx.x;

#define ACCB(w, b, e) do {                                   \
        float v_ = (((w) >> (8*(b))) & 1u) ? (e) : 0.0f;     \
        s += v_; s2 = fmaf(v_, (e), s2);                     \
    } while (0)

    #pragma unroll
    for (int it = 0; it < ITERS; ++it) {
        const int i = base + it * SPAN;
        const uint4  m  = mv[i];
        const float4 e0 = embv[4*i + 0];
        const float4 e1 = embv[4*i + 1];
        const float4 e2 = embv[4*i + 2];
        const float4 e3 = embv[4*i + 3];

        unsigned int t = m.x + m.y + m.z + m.w;   // per-byte sums <= 4
        cnt_i += (t * 0x01010101u) >> 24;         // sum of 16 mask bytes

        ACCB(m.x,0,e0.x); ACCB(m.x,1,e0.y); ACCB(m.x,2,e0.z); ACCB(m.x,3,e0.w);
        ACCB(m.y,0,e1.x); ACCB(m.y,1,e1.y); ACCB(m.y,2,e1.z); ACCB(m.y,3,e1.w);
        ACCB(m.z,0,e2.x); ACCB(m.z,1,e2.y); ACCB(m.z,2,e2.z); ACCB(m.z,3,e2.w);
        ACCB(m.w,0,e3.x); ACCB(m.w,1,e3.y); ACCB(m.w,2,e3.z); ACCB(m.w,3,e3.w);
    }
#undef ACCB

    float cnt = (float)cnt_i;
    #pragma unroll
    for (int off = 32; off > 0; off >>= 1) {
        cnt += __shfl_down(cnt, off);
        s   += __shfl_down(s,   off);
        s2  += __shfl_down(s2,  off);
    }

    __shared__ float sm[3][BT / 64];
    __shared__ int role;
    {
        const int lane = threadIdx.x & 63;
        const int wv   = threadIdx.x >> 6;
        if (lane == 0) { sm[0][wv] = cnt; sm[1][wv] = s; sm[2][wv] = s2; }
    }
    __syncthreads();
    if (threadIdx.x == 0) {
        float tc = 0.f, ts = 0.f, t2 = 0.f;
        #pragma unroll
        for (int w = 0; w < BT / 64; ++w) {
            tc += sm[0][w]; ts += sm[1][w]; t2 += sm[2][w];
        }
        float* dst = ws + (size_t)blk * P_STRIDE;
        dst[0 * NK + nk] = tc;
        dst[1 * NK + nk] = ts;
        dst[2 * NK + nk] = t2;
        __threadfence();                          // release partials
        unsigned int* cntp = (unsigned int*)ws + CNT_BASE;
        unsigned int old = atomicAdd(&cntp[nk * CNT_STRIDE], 1u);
        role = (old == BPN - 1) ? 1 : 0;          // last arrival for this nk
    }
    __syncthreads();
    if (!role || threadIdx.x >= 64) return;

    // ---- level 1: per-nk finalizer (one wave) ----
    __threadfence();                              // acquire partials
    const int lane = threadIdx.x;
    float fc = 0.f, fs = 0.f, f2 = 0.f;
    if (lane < BPN) {
        const float* src = ws + (size_t)lane * P_STRIDE;
        fc = src[0 * NK + nk];
        fs = src[1 * NK + nk];
        f2 = src[2 * NK + nk];
    }
    #pragma unroll
    for (int off = 16; off > 0; off >>= 1) {
        fc += __shfl_down(fc, off, 32);
        fs += __shfl_down(fs, off, 32);
        f2 += __shfl_down(f2, off, 32);
    }
    int img_last = 0;
    if (lane == 0) {
        const bool valid = fc > 0.0f;
        const float safe = valid ? fc : 1.0f;
        const float mean = valid ? fs / safe : 0.0f;
        const float var  = valid ? f2 / safe - mean * mean : 0.0f;
        ws[WS_MEAN + nk] = mean;
        ws[WS_VAR  + nk] = var;
        __threadfence();                          // release mean/var
        unsigned int* cntp = (unsigned int*)ws + CNT_BASE;
        unsigned int o = atomicAdd(&cntp[(NK + n) * CNT_STRIDE], 1u);
        img_last = (o == K_OBJ - 1) ? 1 : 0;
    }
    img_last = __shfl(img_last, 0);
    if (!img_last) return;

    // ---- level 2: per-image epilogue (one wave, lanes 0..31) ----
    __threadfence();                              // acquire means/vars
    float mk = 0.f, vk = 0.f; int ck = -1;
    if (lane < K_OBJ) {
        mk = ws[WS_MEAN + n * K_OBJ + lane];
        vk = ws[WS_VAR  + n * K_OBJ + lane];
        ck = classes[n * K_OBJ + lane];
    }
    float part = (lane < K_OBJ) ? (mk * mk + vk) * (1.0f / K_OBJ) : 0.f;
    for (int r = 1; r < K_OBJ; ++r) {
        const int src = (lane + r) & (K_OBJ - 1);
        const float mo = __shfl(mk, src, 32);
        const int   co = __shfl(ck, src, 32);
        if (lane < K_OBJ && src > lane && co == ck) {
            const float d = mk - mo;
            const float val = 1.0f - d * d;
            part += (val > 0.0f) ? val : 0.0f;
        }
    }
    #pragma unroll
    for (int off = 16; off > 0; off >>= 1) part += __shfl_down(part, off, 32);
    int glob_last = 0;
    if (lane == 0) {
        ws[WS_PIMG + n] = part;
        __threadfence();                          // release image part
        unsigned int* cntp = (unsigned int*)ws + CNT_BASE;
        unsigned int o = atomicAdd(&cntp[(NK + N_IMG) * CNT_STRIDE], 1u);
        glob_last = (o == N_IMG - 1) ? 1 : 0;
    }
    glob_last = __shfl(glob_last, 0);
    if (!glob_last) return;

    // ---- level 3: final scalar ----
    __threadfence();                              // acquire image parts
    if (lane == 0)
        out[0] = (ws[WS_PIMG + 0] + ws[WS_PIMG + 1]) * (0.1f / N_IMG);
}

extern "C" void kernel_launch(void* const* d_in, const int* in_sizes, int n_in,
                              void* d_out, int out_size, void* d_ws, size_t ws_size,
                              hipStream_t stream) {
    const float* pred = (const float*)d_in[0];
    const unsigned char* mask = (const unsigned char*)d_in[1];
    const int* classes = (const int*)d_in[2];
    float* out = (float*)d_out;
    float* ws = (float*)d_ws;

    zero_cnt<<<1, 256, 0, stream>>>((unsigned int*)ws + CNT_BASE);
    fused_kernel<<<NK * BPN, BT, 0, stream>>>(pred, mask, classes, ws, out);
}

// Round 12
// 28.874 us; speedup vs baseline: 3.4045x; 3.4045x over previous
//
#include <hip/hip_runtime.h>

// Problem constants (from reference setup_inputs):
//   pred_emb:   (N=2, C=80, H=512, W=512) float32
//   gt_objmask: (N=2, K=32, H=512, W=512) bool (1 byte/elem)
//   gt_classes: (N=2, K=32) int32
#define N_IMG 2
#define K_OBJ 32
#define C_CH  80
#define HW    (512 * 512)
#define NK    (N_IMG * K_OBJ)

#define BPN 32                    // blocks per (n,k)
#define BT  256                   // threads per block
#define SPAN (BPN * BT)           // 8192 thread-slots per (n,k)
#define NV16 (HW / 16)            // 16384 16-elem groups per (n,k)
#define ITERS (NV16 / SPAN)       // = 2, compile-time

// ws layout (dword offsets). All cross-block data goes through ATOMICS only
// (single coherence point per address) — NO __threadfence anywhere (R4/R11
// showed device-fence costs ~60ns x 2048 serialized = ~120us).
//   acc arrays + tickets: one 128B line per element (stride 32 dwords).
#define ACC_CNT(nk) ((nk) * 32)               // [0, 2048)
#define ACC_S(nk)   (2048 + (nk) * 32)        // [2048, 4096)
#define ACC_S2(nk)  (4096 + (nk) * 32)        // [4096, 6144)
#define TK1(nk)     (6144 + (nk) * 32)        // [6144, 8192)
#define TK2(n)      (8192 + (n) * 32)         // [8192, 8256)
#define TK3         8256                      // [8256, 8288)
#define ZERO_WORDS  8288
#define W_MEAN(nk)  (8320 + (nk) * 8)         // atomicExch-written, no zeroing
#define W_VAR(nk)   (8832 + (nk) * 8)
#define W_PART(n)   (9344 + (n) * 8)

#define VM_WAIT() asm volatile("s_waitcnt vmcnt(0)" ::: "memory")

__global__ __launch_bounds__(1024) void zero_ws(float* __restrict__ ws) {
    const int t = threadIdx.x;
    #pragma unroll
    for (int r = 0; r < (ZERO_WORDS + 1023) / 1024; ++r) {
        const int idx = t + r * 1024;
        if (idx < ZERO_WORDS) ws[idx] = 0.0f;
    }
}

__global__ __launch_bounds__(BT) void fused_kernel(
    const float* __restrict__ pred,
    const unsigned char* __restrict__ mask,
    const int* __restrict__ classes,
    float* __restrict__ ws,
    float* __restrict__ out)
{
    const int nk  = blockIdx.x / BPN;
    const int blk = blockIdx.x % BPN;
    const int n   = nk / K_OBJ;
    const int c   = classes[nk];

    const float4* __restrict__ embv =
        (const float4*)(pred + (size_t)(n * C_CH + c) * HW);
    const uint4* __restrict__ mv =
        (const uint4*)(mask + (size_t)nk * HW);

    unsigned int cnt_i = 0;
    float s = 0.0f, s2 = 0.0f;
    const int base = blk * BT + threadIdx.x;

#define ACCB(w, b, e) do {                                   \
        float v_ = (((w) >> (8*(b))) & 1u) ? (e) : 0.0f;     \
        s += v_; s2 = fmaf(v_, (e), s2);                     \
    } while (0)

    #pragma unroll
    for (int it = 0; it < ITERS; ++it) {
        const int i = base + it * SPAN;
        const uint4  m  = mv[i];
        const float4 e0 = embv[4*i + 0];
        const float4 e1 = embv[4*i + 1];
        const float4 e2 = embv[4*i + 2];
        const float4 e3 = embv[4*i + 3];

        unsigned int t = m.x + m.y + m.z + m.w;   // per-byte sums <= 4
        cnt_i += (t * 0x01010101u) >> 24;         // sum of 16 mask bytes

        ACCB(m.x,0,e0.x); ACCB(m.x,1,e0.y); ACCB(m.x,2,e0.z); ACCB(m.x,3,e0.w);
        ACCB(m.y,0,e1.x); ACCB(m.y,1,e1.y); ACCB(m.y,2,e1.z); ACCB(m.y,3,e1.w);
        ACCB(m.z,0,e2.x); ACCB(m.z,1,e2.y); ACCB(m.z,2,e2.z); ACCB(m.z,3,e2.w);
        ACCB(m.w,0,e3.x); ACCB(m.w,1,e3.y); ACCB(m.w,2,e3.z); ACCB(m.w,3,e3.w);
    }
#undef ACCB

    float cnt = (float)cnt_i;
    #pragma unroll
    for (int off = 32; off > 0; off >>= 1) {
        cnt += __shfl_down(cnt, off);
        s   += __shfl_down(s,   off);
        s2  += __shfl_down(s2,  off);
    }

    __shared__ float sm[3][BT / 64];
    __shared__ int role;
    {
        const int lane = threadIdx.x & 63;
        const int wv   = threadIdx.x >> 6;
        if (lane == 0) { sm[0][wv] = cnt; sm[1][wv] = s; sm[2][wv] = s2; }
    }
    __syncthreads();
    if (threadIdx.x == 0) {
        float tc = 0.f, ts = 0.f, t2 = 0.f;
        #pragma unroll
        for (int w = 0; w < BT / 64; ++w) {
            tc += sm[0][w]; ts += sm[1][w]; t2 += sm[2][w];
        }
        // accumulate directly into device-coherent accumulators (no fence)
        atomicAdd(&ws[ACC_CNT(nk)], tc);
        atomicAdd(&ws[ACC_S(nk)],   ts);
        atomicAdd(&ws[ACC_S2(nk)],  t2);
        VM_WAIT();   // data-atomics acked at coherence point before ticket
        unsigned int old = atomicAdd((unsigned int*)ws + TK1(nk), 1u);
        role = (old == BPN - 1) ? 1 : 0;          // last arrival for this nk
    }
    __syncthreads();
    if (!role || threadIdx.x >= 64) return;

    // ---- level 1: per-nk mean/var (lane 0 of the surviving wave) ----
    const int lane = threadIdx.x;
    int img_last = 0;
    if (lane == 0) {
        const float fc = atomicAdd(&ws[ACC_CNT(nk)], 0.0f);  // atomic read
        const float fs = atomicAdd(&ws[ACC_S(nk)],   0.0f);
        const float f2 = atomicAdd(&ws[ACC_S2(nk)],  0.0f);
        const bool valid = fc > 0.0f;
        const float safe = valid ? fc : 1.0f;
        const float mean = valid ? fs / safe : 0.0f;
        const float var  = valid ? f2 / safe - mean * mean : 0.0f;
        atomicExch(&ws[W_MEAN(nk)], mean);
        atomicExch(&ws[W_VAR(nk)],  var);
        VM_WAIT();
        unsigned int o = atomicAdd((unsigned int*)ws + TK2(n), 1u);
        img_last = (o == K_OBJ - 1) ? 1 : 0;
    }
    img_last = __shfl(img_last, 0);
    if (!img_last) return;

    // ---- level 2: per-image epilogue (lanes 0..31 hold k=lane) ----
    float mk = 0.f, vk = 0.f; int ck = -1;
    if (lane < K_OBJ) {
        mk = atomicAdd(&ws[W_MEAN(n * K_OBJ + lane)], 0.0f);
        vk = atomicAdd(&ws[W_VAR(n * K_OBJ + lane)],  0.0f);
        ck = classes[n * K_OBJ + lane];
    }
    float part = (lane < K_OBJ) ? (mk * mk + vk) * (1.0f / K_OBJ) : 0.f;
    for (int r = 1; r < K_OBJ; ++r) {
        const int src = (lane + r) & (K_OBJ - 1);
        const float mo = __shfl(mk, src, 32);
        const int   co = __shfl(ck, src, 32);
        if (lane < K_OBJ && src > lane && co == ck) {
            const float d = mk - mo;
            const float val = 1.0f - d * d;
            part += (val > 0.0f) ? val : 0.0f;
        }
    }
    #pragma unroll
    for (int off = 16; off > 0; off >>= 1) part += __shfl_down(part, off, 32);
    int glob_last = 0;
    if (lane == 0) {
        atomicExch(&ws[W_PART(n)], part);
        VM_WAIT();
        unsigned int o = atomicAdd((unsigned int*)ws + TK3, 1u);
        glob_last = (o == N_IMG - 1) ? 1 : 0;
    }
    glob_last = __shfl(glob_last, 0);
    if (!glob_last) return;

    // ---- level 3: final scalar ----
    if (lane == 0) {
        const float p0 = atomicAdd(&ws[W_PART(0)], 0.0f);
        const float p1 = atomicAdd(&ws[W_PART(1)], 0.0f);
        out[0] = (p0 + p1) * (0.1f / N_IMG);
    }
}

extern "C" void kernel_launch(void* const* d_in, const int* in_sizes, int n_in,
                              void* d_out, int out_size, void* d_ws, size_t ws_size,
                              hipStream_t stream) {
    const float* pred = (const float*)d_in[0];
    const unsigned char* mask = (const unsigned char*)d_in[1];
    const int* classes = (const int*)d_in[2];
    float* out = (float*)d_out;
    float* ws = (float*)d_ws;

    zero_ws<<<1, 1024, 0, stream>>>(ws);
    fused_kernel<<<NK * BPN, BT, 0, stream>>>(pred, mask, classes, ws, out);
}